// Round 2
// baseline (721.304 us; speedup 1.0000x reference)
//
#include <hip/hip_runtime.h>

// H=W=1024, T=16, 20 iterations. Intermediates live in two padded+guarded
// zero-bordered buffers. Layout per buffer (floats):
//   [16 slack][guard row][row 0 (border)] ... [row 1025 (border)][guard row]
// PITCH=1040 leaves a 14-float zero gutter per row. All guards/gutters/borders
// are memset-zero once and never written, so ANY clamped sample index reads
// exact 0.0 for out-of-range corners (zeros padding is exact, no per-lane
// validity cmp/cndmask).
//
// R7 structure (vs R6):
//  - The gather is L1 address-divergence bound (~20 lines/wave-instr). Per
//    (tile, transform), setup_tiles computes the clamped sample-cell bbox; if
//    it fits a 4K-float budget, ifs_iter COALESCED-stages that rect into LDS
//    and performs the bilinear gathers from LDS (divergence ~free there).
//  - LDS rect pitch = pow2(dx)+1 to spread banks; direct-gather fallback for
//    oversized rects (block-uniform branch).
//  - Values staged are bit-identical to what the direct path reads, so the
//    arithmetic (and absmax) is unchanged.
constexpr int W = 1024;
constexpr int H = 1024;
constexpr int T = 16;
constexpr int ITERS = 20;
constexpr int PITCH = 1040;              // floats per row
constexpr int PH = H + 2;                // 1026 logical padded rows
constexpr int GROWS = PH + 2;            // + guard row above and below
constexpr int ALLOC = 16 + GROWS * PITCH;  // floats per buffer allocation
constexpr int TILES_X = W / 16;          // 64
constexpr int TILES_Y = H / 16;          // 64
constexpr int NTILES = TILES_X * TILES_Y;
constexpr int ENT = 16;                  // floats per (tile,transform) entry
constexpr int LDS_FLOATS = 4608;         // 4096 data + <=511 pad + 1

typedef float f2 __attribute__((ext_vector_type(2), aligned(4)));

// coef per transform t: {p, Ax, Bx, Cxb, Ay, By, Cyb}; Cxb/Cyb include the
// +1 pad shift AND +1 gather-base bias, so xb = Ax*w + Bx*h + Cxb is the
// padded x coordinate + 1 (>= 0 for any in-range sample).
__global__ void setup_coef(const float* __restrict__ theta,
                           const float* __restrict__ probs,
                           float* __restrict__ coef) {
    int t = threadIdx.x;
    if (t >= T) return;
    float sum = 0.f;
    for (int i = 0; i < T; ++i) sum += probs[i];
    float p = probs[t] / sum;
    const float* th = theta + 6 * t;
    float a = th[0], b = th[1], c = th[2];
    float d = th[3], e = th[4], f = th[5];
    float Cx = a * ((1.0f - (float)W) * 0.5f)
             + b * ((1.0f - (float)H) * 0.5f)
             + (c + 1.0f) * ((float)W * 0.5f) - 0.5f;
    float Cy = d * ((1.0f - (float)W) * 0.5f)
             + e * ((1.0f - (float)H) * 0.5f)
             + (f + 1.0f) * ((float)H * 0.5f) - 0.5f;
    float* o = coef + 8 * t;
    o[0] = p;  o[1] = a;  o[2] = b;  o[3] = Cx + 2.0f;
    o[4] = d;  o[5] = e;  o[6] = Cy + 2.0f; o[7] = 0.f;
}

// One thread per 16x16 tile: conservative bbox hit test (exact skip), compact
// active transforms into 16-float entries:
//   [0..6] p,Ax,Bx,Cxb,Ay,By,Cyb   [7] int bits: (log2(dxp)<<1)|staged
//   [8] (float)rx0  [9] (float)ry0  [10] int bits: ry0*PITCH+rx0 (cell base)
//   [11] int bits: n = dy<<s (staged element count)   [12] (float)(dxp+1)
__global__ __launch_bounds__(256) void setup_tiles(const float* __restrict__ coef,
                                                   float* __restrict__ tbl,
                                                   int* __restrict__ tcnt) {
    int tile = blockIdx.x * 256 + threadIdx.x;
    if (tile >= NTILES) return;
    int tx = tile & (TILES_X - 1), ty = tile >> 6;
    float w0 = (float)(tx * 16), w1 = w0 + 15.f;
    float h0 = (float)(ty * 16), h1 = h0 + 15.f;
    float* o0 = tbl + tile * (T * ENT);
    int n = 0;
    for (int t = 0; t < T; ++t) {
        const float* c = coef + t * 8;
        float Ax = c[1], Bx = c[2], Cx = c[3];
        float Ay = c[4], By = c[5], Cy = c[6];
        float xmin = Cx + (Ax >= 0.f ? Ax * w0 : Ax * w1) + (Bx >= 0.f ? Bx * h0 : Bx * h1);
        float xmax = Cx + (Ax >= 0.f ? Ax * w1 : Ax * w0) + (Bx >= 0.f ? Bx * h1 : Bx * h0);
        float ymin = Cy + (Ay >= 0.f ? Ay * w0 : Ay * w1) + (By >= 0.f ? By * h0 : By * h1);
        float ymax = Cy + (Ay >= 0.f ? Ay * w1 : Ay * w0) + (By >= 0.f ? By * h1 : By * h0);
        bool hit = !(xmax <= 1.f || xmin >= (float)(W + 2) ||
                     ymax <= 1.f || ymin >= (float)(H + 2));
        if (!hit) continue;
        // clamped cell bbox (monotone clamp => covers every sample's 4 cells)
        float cx0 = fminf(fmaxf(xmin, 0.f), 1037.f);
        float cx1 = fminf(fmaxf(xmax, 0.f), 1037.f);
        float cy0 = fminf(fmaxf(ymin, 0.f), 1026.f);
        float cy1 = fminf(fmaxf(ymax, 0.f), 1026.f);
        int xi0 = (int)floorf(cx0), xi1 = (int)floorf(cx1);
        int yi0 = (int)floorf(cy0), yi1 = (int)floorf(cy1);
        int dx = xi1 - xi0 + 2;           // cells cols [xi0, xi1+1]
        int dy = yi1 - yi0 + 2;           // cells rows [yi0, yi1+1]
        int s = 1;
        while ((1 << s) < dx) ++s;
        int dxp = 1 << s;
        bool staged = (dxp * dy <= 4096) && (dy <= 511);
        float* o = o0 + n * ENT;
        o[0] = c[0]; o[1] = Ax; o[2] = Bx; o[3] = Cx;
        o[4] = Ay;   o[5] = By; o[6] = Cy;
        o[7] = __int_as_float((s << 1) | (staged ? 1 : 0));
        o[8] = (float)xi0;
        o[9] = (float)yi0;
        o[10] = __int_as_float(yi0 * PITCH + xi0);
        o[11] = __int_as_float(dy << s);
        o[12] = (float)(dxp + 1);
        o[13] = 0.f; o[14] = 0.f; o[15] = 0.f;
        ++n;
    }
    tcnt[tile] = n;
}

__global__ __launch_bounds__(256) void copy_in(const float* __restrict__ src,
                                               float* __restrict__ dst) {
    int i = blockIdx.x * 256 + threadIdx.x;   // i in [0, H*W)
    int h = i >> 10, w = i & 1023;
    dst[(h + 1) * PITCH + (w + 1)] = src[i];
}

__global__ __launch_bounds__(256) void ifs_iter(const float* __restrict__ in,
                                                float* __restrict__ out,
                                                const float* __restrict__ tbl,
                                                const int* __restrict__ tcnt,
                                                const float* __restrict__ base,
                                                int dstPitch, int dstOff,
                                                int add_base) {
    __shared__ float lds[LDS_FLOATS];

    int tile = blockIdx.y * TILES_X + blockIdx.x;
    const float* tc = tbl + tile * (T * ENT);   // uniform
    int nact = tcnt[tile];                      // uniform

    // 8x8-per-wave mapping; 4 waves tile a 16x16 pixel block.
    int lid = threadIdx.x;
    int lane = lid & 63, wv = lid >> 6;
    int w = (blockIdx.x << 4) + ((wv & 1) << 3) + (lane & 7);
    int h = (blockIdx.y << 4) + ((wv >> 1) << 3) + (lane >> 3);
    float wf = (float)w, hf = (float)h;
    // gather base: cell (r,c) = gb[r*PITCH + c]; r=yi..yi+1, c=xi..xi+1
    const float* gb = in - (PITCH + 1);

    float acc = 0.f;

    for (int g = 0; g < nact; ++g) {
        const float* c = tc + g * ENT;          // uniform -> s_load
        float p = c[0], Ax = c[1], Bx = c[2], Cx = c[3];
        float Ay = c[4], By = c[5], Cy = c[6];
        int flags = __float_as_int(c[7]);       // uniform

        float xb = fmaf(Ax, wf, fmaf(Bx, hf, Cx));
        float yb = fmaf(Ay, wf, fmaf(By, hf, Cy));
        float xc = fminf(fmaxf(xb, 0.f), 1037.f);  // v_med3
        float yc = fminf(fmaxf(yb, 0.f), 1026.f);

        if (flags & 1) {
            // ---- staged path (block-uniform branch) ----
            int s_ = flags >> 1;
            float rx0f = c[8], ry0f = c[9];
            int base0 = __float_as_int(c[10]);
            int n = __float_as_int(c[11]);
            int stride2 = PITCH - (1 << s_);    // row*PITCH+col = base0+row*stride2+i

            // coalesced stage: cell(row, col) -> lds[row*(dxp+1)+col] = lds[i+row]
            {
                int i = lid;
                if (i < n) {
                    int row = i >> s_;
                    float v = gb[base0 + row * stride2 + i];
                    for (;;) {
                        int i2 = i + 256;
                        bool more = i2 < n;
                        int row2 = 0; float v2 = 0.f;
                        if (more) {             // prefetch next before store
                            row2 = i2 >> s_;
                            v2 = gb[base0 + row2 * stride2 + i2];
                        }
                        lds[i + row] = v;
                        if (!more) break;
                        i = i2; row = row2; v = v2;
                    }
                }
            }
            __syncthreads();

            float xr = xc - rx0f, yr = yc - ry0f;
            float lxf = floorf(xr), lyf = floorf(yr);
            float fx = xr - lxf, fy = yr - lyf;
            float pitchf = c[12];
            int la = (int)fmaf(lyf, pitchf, lxf);   // exact (< 2^24)
            int pitchI = (1 << s_) + 1;
            float v00 = lds[la],          v01 = lds[la + 1];
            float v10 = lds[la + pitchI], v11 = lds[la + pitchI + 1];
            float top = fmaf(fx, v01 - v00, v00);
            float bot = fmaf(fx, v11 - v10, v10);
            acc = fmaf(p, fmaf(fy, bot - top, top), acc);
            __syncthreads();
        } else {
            // ---- direct-gather fallback (rare oversized rects) ----
            float xi = floorf(xc), yi = floorf(yc);
            float fx = xc - xi, fy = yc - yi;
            int off = (int)fmaf(yi, (float)PITCH, xi);  // exact (< 2^24)
            f2 r0 = *(const f2*)(gb + off);
            f2 r1 = *(const f2*)(gb + off + PITCH);
            float top = fmaf(fx, r0.y - r0.x, r0.x);
            float bot = fmaf(fx, r1.y - r1.x, r1.x);
            acc = fmaf(p, fmaf(fy, bot - top, top), acc);
        }
    }

    if (add_base) acc += base[0];
    out[h * dstPitch + w + dstOff] = acc;
}

extern "C" void kernel_launch(void* const* d_in, const int* in_sizes, int n_in,
                              void* d_out, int out_size, void* d_ws, size_t ws_size,
                              hipStream_t stream) {
    const float* canvas0 = (const float*)d_in[0];
    const float* theta   = (const float*)d_in[1];
    const float* probs   = (const float*)d_in[2];
    const float* base    = (const float*)d_in[3];

    float* raw  = (float*)d_ws;
    float* bufA = raw + 16 + PITCH;                 // logical padded base
    float* bufB = raw + ALLOC + 16 + PITCH;
    float* coef = raw + 2 * ALLOC;
    float* tbl  = coef + T * 8;
    int*   tcnt = (int*)(tbl + NTILES * T * ENT);

    // zero both buffer allocations: borders, gutters, guard rows, slack
    hipMemsetAsync(raw, 0, (size_t)2 * ALLOC * sizeof(float), stream);

    setup_coef<<<1, 64, 0, stream>>>(theta, probs, coef);
    setup_tiles<<<(NTILES + 255) / 256, 256, 0, stream>>>(coef, tbl, tcnt);
    copy_in<<<(H * W) / 256, 256, 0, stream>>>(canvas0, bufA);

    dim3 block(256);
    dim3 grid(TILES_X, TILES_Y);

    const float* cur = bufA;
    for (int i = 0; i < ITERS; ++i) {
        bool last = (i == ITERS - 1);
        float* dst = last ? (float*)d_out : ((i & 1) ? bufA : bufB);
        int dstPitch = last ? W : PITCH;
        int dstOff   = last ? 0 : (PITCH + 1);
        ifs_iter<<<grid, block, 0, stream>>>(cur, dst, tbl, tcnt, base,
                                             dstPitch, dstOff, last ? 1 : 0);
        cur = dst;
    }
}

// Round 3
// 376.521 us; speedup vs baseline: 1.9157x; 1.9157x over previous
//
#include <hip/hip_runtime.h>

// H=W=1024, T=16, 20 iterations.
//
// R8: intermediates live in two VERTICAL-PAIR buffers:
//   buf2[r][c] = ( pad[r-1][c-1], pad[r][c-1] )   (float2, 8 B)
// where pad[y][x] is the zero-bordered padded canvas (pixel (h,w) at
// pad[h+1][w+1]). The 4 bilinear corners of a sample live in TWO ADJACENT f2
// elements -> ONE 16B dwordx4 gather per (pixel, transform) instead of two
// dwordx2 gathers. Guards/gutters are memset-zero once and never written, so
// clamped OOB samples read exact 0.0 (zeros padding exact, no per-lane cmp).
//
// Coordinates: xb = Ax*w + Bx*h + Cxb is padded-x + 1 (clamp bias), clamped to
// [0,1037]; yb likewise to [0,1026]. Cell read: buf2[yi][xi..xi+1] where
// xi=floor(xb), yi=floor(yb) -> corners pad[yi-1..yi][xi-1..xi].
constexpr int W = 1024;
constexpr int H = 1024;
constexpr int T = 16;
constexpr int ITERS = 20;
constexpr int P2 = 1040;                 // f2 elements per row (8320 B, 64B-aligned rows)
constexpr int ROWS2 = 1027;              // rows 0..1026 readable
constexpr int ALLOC2F = ROWS2 * P2 * 2;  // floats per pair-buffer allocation
constexpr int TILES_X = W / 16;          // 64
constexpr int TILES_Y = H / 16;          // 64
constexpr int NTILES = TILES_X * TILES_Y;

typedef float f2 __attribute__((ext_vector_type(2), aligned(8)));
typedef float f4 __attribute__((ext_vector_type(4), aligned(8)));  // 8B-aligned ok

// coef per transform t: {p, Ax, Bx, Cxb, Ay, By, Cyb, 0}; Cxb/Cyb include the
// +1 pad shift AND +1 clamp bias.
__global__ void setup_coef(const float* __restrict__ theta,
                           const float* __restrict__ probs,
                           float* __restrict__ coef) {
    int t = threadIdx.x;
    if (t >= T) return;
    float sum = 0.f;
    for (int i = 0; i < T; ++i) sum += probs[i];
    float p = probs[t] / sum;
    const float* th = theta + 6 * t;
    float a = th[0], b = th[1], c = th[2];
    float d = th[3], e = th[4], f = th[5];
    float Cx = a * ((1.0f - (float)W) * 0.5f)
             + b * ((1.0f - (float)H) * 0.5f)
             + (c + 1.0f) * ((float)W * 0.5f) - 0.5f;
    float Cy = d * ((1.0f - (float)W) * 0.5f)
             + e * ((1.0f - (float)H) * 0.5f)
             + (f + 1.0f) * ((float)H * 0.5f) - 0.5f;
    float* o = coef + 8 * t;
    o[0] = p;  o[1] = a;  o[2] = b;  o[3] = Cx + 2.0f;
    o[4] = d;  o[5] = e;  o[6] = Cy + 2.0f; o[7] = 0.f;
}

// One thread per 16x16 tile: conservative bbox hit test (exact skip), compact
// the active transforms' 8-float coef rows, zero-pad count to multiple of 4
// (dummy rows are all-zero -> p=0, off=0 -> exact no-op).
__global__ __launch_bounds__(256) void setup_tiles(const float* __restrict__ coef,
                                                   float* __restrict__ tbl,
                                                   int* __restrict__ tcnt) {
    int tile = blockIdx.x * 256 + threadIdx.x;
    if (tile >= NTILES) return;
    int tx = tile & (TILES_X - 1), ty = tile >> 6;
    float w0 = (float)(tx * 16), w1 = w0 + 15.f;
    float h0 = (float)(ty * 16), h1 = h0 + 15.f;
    float* o = tbl + tile * 128;
    int n = 0;
    for (int t = 0; t < T; ++t) {
        const float* c = coef + t * 8;
        float Ax = c[1], Bx = c[2], Cx = c[3];
        float Ay = c[4], By = c[5], Cy = c[6];
        float xmin = Cx + (Ax >= 0.f ? Ax * w0 : Ax * w1) + (Bx >= 0.f ? Bx * h0 : Bx * h1);
        float xmax = Cx + (Ax >= 0.f ? Ax * w1 : Ax * w0) + (Bx >= 0.f ? Bx * h1 : Bx * h0);
        float ymin = Cy + (Ay >= 0.f ? Ay * w0 : Ay * w1) + (By >= 0.f ? By * h0 : By * h1);
        float ymax = Cy + (Ay >= 0.f ? Ay * w1 : Ay * w0) + (By >= 0.f ? By * h1 : By * h0);
        bool hit = !(xmax <= 1.f || xmin >= (float)(W + 2) ||
                     ymax <= 1.f || ymin >= (float)(H + 2));
        if (hit) {
            for (int j = 0; j < 8; ++j) o[n * 8 + j] = c[j];
            ++n;
        }
    }
    tcnt[tile] = n;
    int np = (n + 3) & ~3;
    for (int s = n; s < np; ++s)
        for (int j = 0; j < 8; ++j) o[s * 8 + j] = 0.f;
}

// Build initial pair buffer from canvas0: pixel (h,w) value v contributes
// buf2[h+2][w+2].x = v and buf2[h+1][w+2].y = v. Borders stay memset-zero.
__global__ __launch_bounds__(256) void copy_in(const float* __restrict__ src,
                                               float* __restrict__ dstf) {
    int i = blockIdx.x * 256 + threadIdx.x;   // i in [0, H*W)
    int h = i >> 10, w = i & 1023;
    float v = src[i];
    int c = w + 2;
    dstf[(((h + 2) * P2) + c) * 2 + 0] = v;
    dstf[(((h + 1) * P2) + c) * 2 + 1] = v;
}

// K transforms per group: coefs via uniform scalar loads; one f4 gather per
// transform fetches all 4 corners (v00,v10,v01,v11).
template <int K>
__device__ __forceinline__ void ifs_body(const float* __restrict__ tc, int g,
                                         const f2* __restrict__ gb,
                                         float wf, float hf, float& acc) {
    float fx[K], fy[K], pp[K];
    int off[K];
#pragma unroll
    for (int k = 0; k < K; ++k) {
        const float* c = tc + (g + k) * 8;          // uniform -> s_load
        float p = c[0], Ax = c[1], Bx = c[2], Cx = c[3];
        float Ay = c[4], By = c[5], Cy = c[6];
        float xb = fmaf(Ax, wf, fmaf(Bx, hf, Cx));
        float yb = fmaf(Ay, wf, fmaf(By, hf, Cy));
        float xc = fminf(fmaxf(xb, 0.f), 1037.f);   // v_med3
        float yc = fminf(fmaxf(yb, 0.f), 1026.f);
        float xi = floorf(xc), yi = floorf(yc);
        fx[k] = xc - xi;
        fy[k] = yc - yi;
        off[k] = (int)fmaf(yi, (float)P2, xi);      // exact (< 2^24)
        pp[k] = p;
    }
    f4 q[K];
#pragma unroll
    for (int k = 0; k < K; ++k)                     // K gathers in flight
        q[k] = *(const f4*)(gb + off[k]);
#pragma unroll
    for (int k = 0; k < K; ++k) {
        // q = (v00, v10, v01, v11)
        float top = fmaf(fx[k], q[k].z - q[k].x, q[k].x);
        float bot = fmaf(fx[k], q[k].w - q[k].y, q[k].y);
        acc = fmaf(pp[k], fmaf(fy[k], bot - top, top), acc);
    }
}

__global__ __launch_bounds__(256) void ifs_iter(const float* __restrict__ inf,
                                                float* __restrict__ dstf,
                                                const float* __restrict__ tbl,
                                                const int* __restrict__ tcnt,
                                                const float* __restrict__ base,
                                                int last) {
    int tile = blockIdx.y * TILES_X + blockIdx.x;
    const float* tc = tbl + tile * 128;             // uniform
    int np = (tcnt[tile] + 3) & ~3;                 // uniform trip count

    // 8x8-per-wave mapping; 4 waves tile a 16x16 pixel block.
    int lid = threadIdx.x;
    int lane = lid & 63, wv = lid >> 6;
    int w = (blockIdx.x << 4) + ((wv & 1) << 3) + (lane & 7);
    int h = (blockIdx.y << 4) + ((wv >> 1) << 3) + (lane >> 3);
    float wf = (float)w, hf = (float)h;
    const f2* gb = (const f2*)inf;

    float acc = 0.f;
    int g = 0;
    for (; g + 8 <= np; g += 8) ifs_body<8>(tc, g, gb, wf, hf, acc);
    if (g < np)                 ifs_body<4>(tc, g, gb, wf, hf, acc);

    if (last) {
        out_write:
        dstf[(h << 10) + w] = acc + base[0];
    } else {
        int c = w + 2;
        dstf[(((h + 2) * P2) + c) * 2 + 0] = acc;
        dstf[(((h + 1) * P2) + c) * 2 + 1] = acc;
    }
}

extern "C" void kernel_launch(void* const* d_in, const int* in_sizes, int n_in,
                              void* d_out, int out_size, void* d_ws, size_t ws_size,
                              hipStream_t stream) {
    const float* canvas0 = (const float*)d_in[0];
    const float* theta   = (const float*)d_in[1];
    const float* probs   = (const float*)d_in[2];
    const float* base    = (const float*)d_in[3];

    float* raw   = (float*)d_ws;
    float* bufAf = raw;
    float* bufBf = raw + ALLOC2F;
    float* coef  = raw + 2 * ALLOC2F;
    float* tbl   = coef + T * 8;
    int*   tcnt  = (int*)(tbl + NTILES * 128);

    // zero both pair buffers: borders, gutters, guards (and kills poison)
    hipMemsetAsync(raw, 0, (size_t)2 * ALLOC2F * sizeof(float), stream);

    setup_coef<<<1, 64, 0, stream>>>(theta, probs, coef);
    setup_tiles<<<(NTILES + 255) / 256, 256, 0, stream>>>(coef, tbl, tcnt);
    copy_in<<<(H * W) / 256, 256, 0, stream>>>(canvas0, bufAf);

    dim3 block(256);
    dim3 grid(TILES_X, TILES_Y);

    const float* cur = bufAf;
    for (int i = 0; i < ITERS; ++i) {
        bool last = (i == ITERS - 1);
        float* dst = last ? (float*)d_out : ((i & 1) ? bufAf : bufBf);
        ifs_iter<<<grid, block, 0, stream>>>(cur, dst, tbl, tcnt, base,
                                             last ? 1 : 0);
        cur = dst;
    }
}